// Round 8
// baseline (52.854 us; speedup 1.0000x reference)
//
#include <hip/hip_runtime.h>
#include <math.h>

#define D      2048
#define KSEL   256
#define NT     256          // 4 waves per block, each wave owns one row
#define NBINS  512          // bins of width 1/64 over |z| in [0,8)
#define WPB    4

typedef float  f4 __attribute__((ext_vector_type(4)));
typedef int    i4 __attribute__((ext_vector_type(4)));
typedef __fp16 h2 __attribute__((ext_vector_type(2)));

// tanh-form GELU: x * sigmoid(1.5957691*x + 0.0713548*x^3)
__device__ __forceinline__ float fast_gelu(float x) {
    float x2 = x * x;
    float t  = fmaf(x2, -0.0713548162f, -1.5957691216f);
    float e  = __expf(x * t);
    return x * __builtin_amdgcn_rcpf(1.0f + e);
}

// ---- DPP cross-lane (VALU pipe, no LDS) ----
template<int CTRL, int RMASK>
__device__ __forceinline__ float dpp_mov_f(float v) {
    int r = __builtin_amdgcn_update_dpp(0, __builtin_bit_cast(int, v),
                                        CTRL, RMASK, 0xf, true);
    return __builtin_bit_cast(float, r);
}
template<int CTRL, int RMASK>
__device__ __forceinline__ int dpp_mov_i(int v) {
    return __builtin_amdgcn_update_dpp(0, v, CTRL, RMASK, 0xf, true);
}
// inclusive prefix ops across 64 lanes; lane 63 ends with the wave total
__device__ __forceinline__ float wave_scan_f(float x) {
    x += dpp_mov_f<0x111, 0xf>(x);
    x += dpp_mov_f<0x112, 0xf>(x);
    x += dpp_mov_f<0x114, 0xf>(x);
    x += dpp_mov_f<0x118, 0xf>(x);
    x += dpp_mov_f<0x142, 0xa>(x);
    x += dpp_mov_f<0x143, 0xc>(x);
    return x;
}
__device__ __forceinline__ int wave_scan_i(int x) {
    x += dpp_mov_i<0x111, 0xf>(x);
    x += dpp_mov_i<0x112, 0xf>(x);
    x += dpp_mov_i<0x114, 0xf>(x);
    x += dpp_mov_i<0x118, 0xf>(x);
    x += dpp_mov_i<0x142, 0xa>(x);
    x += dpp_mov_i<0x143, 0xc>(x);
    return x;
}
__device__ __forceinline__ int wave_or_i(int x) {
    x |= dpp_mov_i<0x111, 0xf>(x);
    x |= dpp_mov_i<0x112, 0xf>(x);
    x |= dpp_mov_i<0x114, 0xf>(x);
    x |= dpp_mov_i<0x118, 0xf>(x);
    x |= dpp_mov_i<0x142, 0xa>(x);
    x |= dpp_mov_i<0x143, 0xc>(x);
    return x;
}
__device__ __forceinline__ float wave_total_f(float x) {
    float s = wave_scan_f(x);
    int r = __builtin_amdgcn_readlane(__builtin_bit_cast(int, s), 63);
    return __builtin_bit_cast(float, r);
}

// ws layout: [0:D) a = 64/std ; [D:2D) b = -64*mean/std ;
//            [2D:3D) u = ema_out/(||ema_out||+1e-8) ; [3D:3D+3) tau,sigma,w
__global__ __launch_bounds__(NT) void prep_kernel(
    const float* __restrict__ ema_mean,
    const float* __restrict__ ema_sq,
    const float* __restrict__ ema_out,
    const float* __restrict__ p_log_tau,
    const float* __restrict__ p_log_sigma,
    const float* __restrict__ p_log_w,
    float* __restrict__ ws)
{
    __shared__ float red[4];
    const int tid = threadIdx.x;
    float ss = 0.f;
#pragma unroll
    for (int k = 0; k < D / NT; ++k) {
        int i = tid + k * NT;
        float m = ema_mean[i];
        float v = fmaxf(fmaf(-m, m, ema_sq[i]), 1e-6f);
        float inv = 64.0f * __builtin_amdgcn_rsqf(v);   // 64/std
        ws[i]     = inv;
        ws[D + i] = -m * inv;
        float e = ema_out[i];
        ss = fmaf(e, e, ss);
    }
    ss = wave_scan_f(ss);
    if ((tid & 63) == 63) red[tid >> 6] = ss;
    __syncthreads();
    float inv_nrm = 1.0f / (sqrtf(red[0] + red[1] + red[2] + red[3]) + 1e-8f);
#pragma unroll
    for (int k = 0; k < D / NT; ++k) {
        int i = tid + k * NT;
        ws[2 * D + i] = ema_out[i] * inv_nrm;
    }
    if (tid == 0) {
        ws[3 * D + 0] = __expf(p_log_tau[0]);
        ws[3 * D + 1] = __logf(1.0f + __expf(p_log_sigma[0])) + 0.01f;
        ws[3 * D + 2] = __logf(1.0f + __expf(p_log_w[0]));
    }
}

// One WAVE per row; no __syncthreads anywhere.
__global__ __launch_bounds__(NT) void row_kernel(
    const float* __restrict__ x,
    const float* __restrict__ ws,
    float* __restrict__ out)
{
    __shared__ int hist[WPB * NBINS];     // per-wave private, REVERSED index

    const int t    = threadIdx.x;
    const int wid  = t >> 6;
    const int lane = t & 63;
    int* __restrict__ h = &hist[wid * NBINS];

    // zero own bins (wave-private; DS ops within a wave execute in order)
    *(i4*)&h[8 * lane]     = (i4)0;
    *(i4*)&h[8 * lane + 4] = (i4)0;

    const float tau   = ws[3 * D + 0];
    const float sigma = ws[3 * D + 1];
    const float w     = ws[3 * D + 2];

    const size_t row = (size_t)blockIdx.x * WPB + wid;
    const float* __restrict__ xr = x + row * D;

    h2 gp[16];       // gelu values, f16-packed
    h2 avp[16];      // 64*|z| values, f16-packed (RTZ: threshold-exact)
    float dot = 0.f, nrm = 0.f;

#pragma unroll
    for (int c = 0; c < 4; ++c) {
        const int vi = c * 128 + 2 * lane;
        f4 x0 = ((const f4*)xr)[vi];
        f4 x1 = ((const f4*)xr)[vi + 1];
        f4 a0 = ((const f4*)ws)[vi];
        f4 a1 = ((const f4*)ws)[vi + 1];
        f4 b0 = ((const f4*)(ws + D))[vi];
        f4 b1 = ((const f4*)(ws + D))[vi + 1];
        f4 u0 = ((const f4*)(ws + 2 * D))[vi];
        f4 u1 = ((const f4*)(ws + 2 * D))[vi + 1];

        const float xv[8] = {x0.x,x0.y,x0.z,x0.w, x1.x,x1.y,x1.z,x1.w};
        const float va[8] = {a0.x,a0.y,a0.z,a0.w, a1.x,a1.y,a1.z,a1.w};
        const float vb[8] = {b0.x,b0.y,b0.z,b0.w, b1.x,b1.y,b1.z,b1.w};
        const float vu[8] = {u0.x,u0.y,u0.z,u0.w, u1.x,u1.y,u1.z,u1.w};

        float gg[8], av[8];
#pragma unroll
        for (int j = 0; j < 8; ++j) {
            gg[j] = fast_gelu(xv[j]);
            av[j] = fabsf(fmaf(xv[j], va[j], vb[j]));   // 64*|z|
            dot = fmaf(gg[j], vu[j], dot);
            nrm = fmaf(gg[j], gg[j], nrm);
            int bin = (int)av[j];
            bin = bin > NBINS - 1 ? NBINS - 1 : bin;
            atomicAdd(&h[(NBINS - 1) - bin], 1);
        }
#pragma unroll
        for (int p = 0; p < 4; ++p) {
            gp[c * 4 + p]  = __builtin_amdgcn_cvt_pkrtz(gg[2*p], gg[2*p+1]);
            avp[c * 4 + p] = __builtin_amdgcn_cvt_pkrtz(av[2*p], av[2*p+1]);
        }
    }

    // ---- wave-local scan of own 512 reversed bins (8 bins/lane) ----
    i4 vA = *(const i4*)&h[8 * lane];
    i4 vB = *(const i4*)&h[8 * lane + 4];
    int c0 = vA.x;
    int c1 = c0 + vA.y;
    int c2 = c1 + vA.z;
    int c3 = c2 + vA.w;
    int c4 = c3 + vB.x;
    int c5 = c4 + vB.y;
    int c6 = c5 + vB.z;
    int c7 = c6 + vB.w;
    int incl = wave_scan_i(c7);
    int excl = incl - c7;                 // elements in bins above this lane's 8
    {
        const int pre[8] = {0, c0, c1, c2, c3, c4, c5, c6};
        const int cum[8] = {c0, c1, c2, c3, c4, c5, c6, c7};
        int enc = 0;
#pragma unroll
        for (int k = 0; k < 8; ++k) {
            int s0 = excl + pre[k];
            int e0 = excl + cum[k];
            if (s0 < KSEL && e0 >= KSEL)
                enc = ((NBINS - 1) - (8 * lane + k)) | ((KSEL - s0) << 16);
        }
        enc = wave_or_i(enc);
        enc = __builtin_amdgcn_readlane(enc, 63);   // uniform broadcast
        excl = enc;                                  // reuse: packed result
    }
    const int   bsel = excl & 0xffff;
    const int   krem = excl >> 16;
    const float thr = (bsel == NBINS - 1) ? __builtin_inff() : (float)(bsel + 1);
    const float mid = (float)bsel + 0.5f;

    // ---- sum of values strictly above boundary bin (from f16 pairs) ----
    float s = 0.f;
#pragma unroll
    for (int i = 0; i < 16; ++i) {
        float lo = (float)avp[i].x;
        float hv = (float)avp[i].y;
        s += (lo >= thr) ? lo : 0.f;
        s += (hv >= thr) ? hv : 0.f;
    }

    dot = wave_total_f(dot);
    nrm = wave_total_f(nrm);
    s   = wave_total_f(s);

    // true topk_sum = (s + krem*mid)/64 ; mean = /KSEL
    const float topk_mean = (s + (float)krem * mid) * (1.0f / (64.0f * KSEL));
    const float cosv = dot * __builtin_amdgcn_rsqf(fmaxf(nrm, 1e-24f));
    const float yt = sigma * topk_mean;
    const float et = __expf(-2.0f * yt);
    const float th = (1.0f - et) * __builtin_amdgcn_rcpf(1.0f + et);  // tanh
    const float gate = __expf(-tau * cosv) * fmaf(w, th, 1.0f);

    f4* __restrict__ outr = (f4*)(out + row * D);
#pragma unroll
    for (int c = 0; c < 4; ++c) {
        f4 o0, o1;
        o0.x = (float)gp[c*4+0].x * gate;
        o0.y = (float)gp[c*4+0].y * gate;
        o0.z = (float)gp[c*4+1].x * gate;
        o0.w = (float)gp[c*4+1].y * gate;
        o1.x = (float)gp[c*4+2].x * gate;
        o1.y = (float)gp[c*4+2].y * gate;
        o1.z = (float)gp[c*4+3].x * gate;
        o1.w = (float)gp[c*4+3].y * gate;
        const int vi = c * 128 + 2 * lane;
        __builtin_nontemporal_store(o0, outr + vi);
        __builtin_nontemporal_store(o1, outr + vi + 1);
    }
}

extern "C" void kernel_launch(void* const* d_in, const int* in_sizes, int n_in,
                              void* d_out, int out_size, void* d_ws, size_t ws_size,
                              hipStream_t stream) {
    (void)n_in; (void)out_size; (void)ws_size;
    const float* x         = (const float*)d_in[0];
    const float* ema_mean  = (const float*)d_in[1];
    const float* ema_sq    = (const float*)d_in[2];
    const float* ema_out   = (const float*)d_in[3];
    const float* log_tau   = (const float*)d_in[4];
    const float* log_sigma = (const float*)d_in[5];
    const float* log_w     = (const float*)d_in[6];
    float* out = (float*)d_out;
    float* ws  = (float*)d_ws;

    prep_kernel<<<1, NT, 0, stream>>>(ema_mean, ema_sq, ema_out,
                                      log_tau, log_sigma, log_w, ws);
    const int rows = in_sizes[0] / D;   // B*T = 16384
    row_kernel<<<rows / WPB, NT, 0, stream>>>(x, ws, out);
}

// Round 9
// 45.844 us; speedup vs baseline: 1.1529x; 1.1529x over previous
//
#include <hip/hip_runtime.h>
#include <math.h>

#define D      2048
#define KSEL   256
#define NT     256          // threads per block; NT*8 == D
#define NBINS  512          // bins of width 1/64 over |z| in [0,8)
#define ROWS   2            // rows per block, processed serially

typedef float f4 __attribute__((ext_vector_type(4)));
typedef int   i4 __attribute__((ext_vector_type(4)));

// tanh-form GELU: x * sigmoid(1.5957691*x + 0.0713548*x^3)
__device__ __forceinline__ float fast_gelu(float x) {
    float x2 = x * x;
    float t  = fmaf(x2, -0.0713548162f, -1.5957691216f);
    float e  = __expf(x * t);
    return x * __builtin_amdgcn_rcpf(1.0f + e);
}

// ---- DPP cross-lane (VALU pipe, no LDS) ----
template<int CTRL, int RMASK>
__device__ __forceinline__ float dpp_mov_f(float v) {
    int r = __builtin_amdgcn_update_dpp(0, __builtin_bit_cast(int, v),
                                        CTRL, RMASK, 0xf, true);
    return __builtin_bit_cast(float, r);
}
template<int CTRL, int RMASK>
__device__ __forceinline__ int dpp_mov_i(int v) {
    return __builtin_amdgcn_update_dpp(0, v, CTRL, RMASK, 0xf, true);
}
// inclusive prefix-sum across 64 lanes; lane 63 ends with the wave total
__device__ __forceinline__ float wave_scan_f(float x) {
    x += dpp_mov_f<0x111, 0xf>(x);   // row_shr:1
    x += dpp_mov_f<0x112, 0xf>(x);   // row_shr:2
    x += dpp_mov_f<0x114, 0xf>(x);   // row_shr:4
    x += dpp_mov_f<0x118, 0xf>(x);   // row_shr:8
    x += dpp_mov_f<0x142, 0xa>(x);   // row_bcast:15 -> rows 1,3
    x += dpp_mov_f<0x143, 0xc>(x);   // row_bcast:31 -> rows 2,3
    return x;
}
__device__ __forceinline__ int wave_scan_i(int x) {
    x += dpp_mov_i<0x111, 0xf>(x);
    x += dpp_mov_i<0x112, 0xf>(x);
    x += dpp_mov_i<0x114, 0xf>(x);
    x += dpp_mov_i<0x118, 0xf>(x);
    x += dpp_mov_i<0x142, 0xa>(x);
    x += dpp_mov_i<0x143, 0xc>(x);
    return x;
}

// Everything fused: no prep kernel, no workspace.
__global__ __launch_bounds__(NT) void row_kernel(
    const float* __restrict__ x,
    const float* __restrict__ ema_mean,
    const float* __restrict__ ema_sq,
    const float* __restrict__ ema_out,
    const float* __restrict__ p_log_tau,
    const float* __restrict__ p_log_sigma,
    const float* __restrict__ p_log_w,
    float* __restrict__ out)
{
    __shared__ int   hist[NBINS];    // REVERSED: hist[NBINS-1-bin]
    __shared__ float ssred[4];
    __shared__ float red[4][3];
    __shared__ int   bsel_sh, krem_sh;

    const int t    = threadIdx.x;
    const int wave = t >> 6;
    const int lane = t & 63;

    // scalar gate params (uniform; cheap redundant compute per block)
    const float tau   = __expf(p_log_tau[0]);
    const float sigma = __logf(1.0f + __expf(p_log_sigma[0])) + 0.01f;
    const float w     = __logf(1.0f + __expf(p_log_w[0]));

    // ---- inline "prep": per-thread channel constants ----
    f4 m0 = ((const f4*)ema_mean)[t];
    f4 m1 = ((const f4*)ema_mean)[t + NT];
    f4 q0 = ((const f4*)ema_sq)[t];
    f4 q1 = ((const f4*)ema_sq)[t + NT];
    f4 e0 = ((const f4*)ema_out)[t];
    f4 e1 = ((const f4*)ema_out)[t + NT];

    const float mv[8] = {m0.x,m0.y,m0.z,m0.w, m1.x,m1.y,m1.z,m1.w};
    const float qv[8] = {q0.x,q0.y,q0.z,q0.w, q1.x,q1.y,q1.z,q1.w};
    const float ev[8] = {e0.x,e0.y,e0.z,e0.w, e1.x,e1.y,e1.z,e1.w};

    float a_[8], b_[8];
    float ss = 0.f;
#pragma unroll
    for (int j = 0; j < 8; ++j) {
        float v = fmaxf(fmaf(-mv[j], mv[j], qv[j]), 1e-6f);
        a_[j] = 64.0f * __builtin_amdgcn_rsqf(v);     // 64/std
        b_[j] = -mv[j] * a_[j];
        ss = fmaf(ev[j], ev[j], ss);
    }
    ss = wave_scan_f(ss);
    if (lane == 63) ssred[wave] = ss;

    const size_t row0 = (size_t)blockIdx.x * ROWS;
    f4 xa = ((const f4*)(x + row0 * D))[t];
    f4 xb = ((const f4*)(x + row0 * D))[t + NT];

    hist[t] = 0;
    hist[t + NT] = 0;
    __syncthreads();                       // B0: hist zeros + ssred visible

    const float inv_nrm =
        1.0f / (sqrtf(ssred[0] + ssred[1] + ssred[2] + ssred[3]) + 1e-8f);
    float u_[8];
#pragma unroll
    for (int j = 0; j < 8; ++j) u_[j] = ev[j] * inv_nrm;

#pragma unroll
    for (int r = 0; r < ROWS; ++r) {
        const float xv[8] = {xa.x,xa.y,xa.z,xa.w, xb.x,xb.y,xb.z,xb.w};

        float g[8], av[8];
        float dot = 0.f, nrm = 0.f;
#pragma unroll
        for (int j = 0; j < 8; ++j) {
            float gg = fast_gelu(xv[j]);
            g[j] = gg;
            av[j] = fabsf(fmaf(xv[j], a_[j], b_[j]));   // 64*|z|
            dot = fmaf(gg, u_[j], dot);
            nrm = fmaf(gg, gg, nrm);
        }

        // prefetch next row's x — latency hides under this row's epilogue
        if (r + 1 < ROWS) {
            const float* xn = x + (row0 + r + 1) * D;
            xa = ((const f4*)xn)[t];
            xb = ((const f4*)xn)[t + NT];
        }

        // reversed-bin histogram
#pragma unroll
        for (int j = 0; j < 8; ++j) {
            int bin = (int)av[j];
            bin = bin > NBINS - 1 ? NBINS - 1 : bin;
            atomicAdd(&hist[(NBINS - 1) - bin], 1);
        }
        __syncthreads();                   // B1: histogram complete

        // wave0: prefix scan over 512 reversed bins (8 bins/lane) + crossing
        if (wave == 0) {
            i4 va = *(const i4*)&hist[8 * lane];
            i4 vb = *(const i4*)&hist[8 * lane + 4];
            int c0 = va.x;
            int c1 = c0 + va.y;
            int c2 = c1 + va.z;
            int c3 = c2 + va.w;
            int c4 = c3 + vb.x;
            int c5 = c4 + vb.y;
            int c6 = c5 + vb.z;
            int c7 = c6 + vb.w;
            int incl = wave_scan_i(c7);
            int excl = incl - c7;          // total of all lanes before this one
            int pre[8] = {0, c0, c1, c2, c3, c4, c5, c6};
            int cum[8] = {c0, c1, c2, c3, c4, c5, c6, c7};
#pragma unroll
            for (int k = 0; k < 8; ++k) {
                int s0 = excl + pre[k];
                int e0x = excl + cum[k];
                if (s0 < KSEL && e0x >= KSEL) {
                    bsel_sh = (NBINS - 1) - (8 * lane + k);
                    krem_sh = KSEL - s0;
                }
            }
        }
        __syncthreads();                   // B2: bsel/krem visible

        const int   bsel = bsel_sh;
        const int   krem = krem_sh;
        const float hi  = (bsel == NBINS - 1) ? __builtin_inff() : (float)(bsel + 1);
        const float mid = (float)bsel + 0.5f;

        float s = 0.f;
#pragma unroll
        for (int j = 0; j < 8; ++j) {
            s += (av[j] >= hi) ? av[j] : 0.f;
        }

        // per-wave reduce via DPP (lane 63 holds totals)
        dot = wave_scan_f(dot);
        nrm = wave_scan_f(nrm);
        s   = wave_scan_f(s);
        if (lane == 63) {
            red[wave][0] = dot; red[wave][1] = nrm; red[wave][2] = s;
        }
        hist[t] = 0;                       // re-zero for next row (pre-B3)
        hist[t + NT] = 0;
        __syncthreads();                   // B3: red + zeros visible

        dot = red[0][0] + red[1][0] + red[2][0] + red[3][0];
        nrm = red[0][1] + red[1][1] + red[2][1] + red[3][1];
        s   = red[0][2] + red[1][2] + red[2][2] + red[3][2];

        // true topk_sum = (s + krem*mid)/64 ; mean = /KSEL
        const float topk_mean = (s + (float)krem * mid) * (1.0f / (64.0f * KSEL));
        const float cosv = dot * __builtin_amdgcn_rsqf(fmaxf(nrm, 1e-24f));
        const float yt = sigma * topk_mean;
        const float et = __expf(-2.0f * yt);
        const float th = (1.0f - et) * __builtin_amdgcn_rcpf(1.0f + et);  // tanh
        const float gate = __expf(-tau * cosv) * fmaf(w, th, 1.0f);

        f4 oa, ob;
        oa.x = g[0]*gate; oa.y = g[1]*gate; oa.z = g[2]*gate; oa.w = g[3]*gate;
        ob.x = g[4]*gate; ob.y = g[5]*gate; ob.z = g[6]*gate; ob.w = g[7]*gate;
        f4* outr = (f4*)(out + (row0 + r) * D);
        outr[t]      = oa;                 // plain stores (NT experiment)
        outr[t + NT] = ob;
    }
}

extern "C" void kernel_launch(void* const* d_in, const int* in_sizes, int n_in,
                              void* d_out, int out_size, void* d_ws, size_t ws_size,
                              hipStream_t stream) {
    (void)n_in; (void)out_size; (void)d_ws; (void)ws_size;
    const float* x         = (const float*)d_in[0];
    const float* ema_mean  = (const float*)d_in[1];
    const float* ema_sq    = (const float*)d_in[2];
    const float* ema_out   = (const float*)d_in[3];
    const float* log_tau   = (const float*)d_in[4];
    const float* log_sigma = (const float*)d_in[5];
    const float* log_w     = (const float*)d_in[6];
    float* out = (float*)d_out;

    const int rows = in_sizes[0] / D;   // B*T = 16384
    row_kernel<<<rows / ROWS, NT, 0, stream>>>(x, ema_mean, ema_sq, ema_out,
                                               log_tau, log_sigma, log_w, out);
}